// Round 11
// baseline (773.558 us; speedup 1.0000x reference)
//
#include <hip/hip_runtime.h>
#include <math.h>

constexpr int NB = 4;      // batch
constexpr int ND = 64;     // feature dim
constexpr int NNN = 4096;  // points
constexpr int NO = 128;    // out channels
constexpr int NK = 16;     // k-nn
constexpr float NEG = 0.01f;
constexpr float BN_EPS = 1e-5f;

typedef unsigned short u16;
typedef unsigned int u32;
typedef __attribute__((ext_vector_type(8))) short short8;
typedef __attribute__((ext_vector_type(4))) float floatx4;

// workspace offsets (in floats)
constexpr int OFF_XX    = 0;
constexpr int OFF_IDX   = 16384;
constexpr int OFF_D2    = 278528;
constexpr int OFF_Q     = 540672;       // qb16 bf16 [b][n][d]
constexpr int OFF_K     = 1589248;      // kb16 bf16 [b][n][d]
constexpr int OFF_V     = 2637824;      // vb16 bf16 [b][d][n]
constexpr int OFF_FGT   = 3686400;      // fgt fp32 [b][n][d] (unnormalized)
constexpr int OFF_APRE  = 4734976;      // bf16 [b][n][o] (u16 in float slot)
constexpr int OFF_BPRE  = 6832128;      // bf16 [b][n][o]
constexpr int OFF_IMAX  = 8929280;
constexpr int OFF_IMIN  = 11026432;
constexpr int OFF_ZSEM  = OFF_Q;
constexpr int OFF_ZFULL = OFF_V;
constexpr int OFF_STATS = 13123584;     // 6*NO: [sum_i,ssq_i | sum_s,ssq_s | sum_f,ssq_f]
constexpr int OFF_COEF  = 13124352;
constexpr int OFF_LINV  = 13125120;

__device__ __forceinline__ u16 f2b(float x) {       // fp32 -> bf16 RNE
  u32 u = __builtin_bit_cast(u32, x);
  u += 0x7fffu + ((u >> 16) & 1u);
  return (u16)(u >> 16);
}
__device__ __forceinline__ float b2f(u16 h) {
  u32 u = (u32)h << 16;
  return __builtin_bit_cast(float, u);
}

// value-only max fold step via DPP (single v_max_f32 with fused DPP src)
template <int CTRL>
__device__ __forceinline__ float fmax_dpp(float v) {
  int b = __builtin_bit_cast(int, v);
  int s = __builtin_amdgcn_update_dpp(b, b, CTRL, 0xF, 0xF, false);
  return fmaxf(v, __builtin_bit_cast(float, s));
}
// (value,col) pair fold: larger value wins; tie -> keep left (smaller col by construction)
__device__ __forceinline__ void pairmax(float av, int ai, float bv, int bi, float& rv, int& ri) {
  bool tk = bv > av;
  rv = tk ? bv : av;
  ri = tk ? bi : ai;
}

// ---------------- xx[b][n] = sum_d f^2 ----------------
__global__ void k_xx(const float* __restrict__ f, float* __restrict__ xx) {
  int gid = blockIdx.x * 256 + threadIdx.x;
  int b = gid >> 12, n = gid & 4095;
  const float* fb = f + b * ND * NNN + n;
  float s = 0.f;
#pragma unroll
  for (int d = 0; d < ND; ++d) { float v = fb[d * NNN]; s += v * v; }
  xx[gid] = s;
}

// ---------------- q/k/v merged: f read ONCE, 3 output sets (bit-identical math) ----------------
__global__ __launch_bounds__(256) void k_qkv(const float* __restrict__ f,
    const float* __restrict__ wq, const float* __restrict__ bq,
    const float* __restrict__ wk, const float* __restrict__ bk,
    const float* __restrict__ wv, const float* __restrict__ bv,
    u16* __restrict__ qb, u16* __restrict__ kb, u16* __restrict__ vb) {
  int t = threadIdx.x;
  int lane = t & 63;
  int og = __builtin_amdgcn_readfirstlane(t >> 6);
  int gcol = blockIdx.x * 64 + lane;
  int b = gcol >> 12, n = gcol & 4095;
  const float* fb = f + b * ND * NNN + n;
  float cv[64];
#pragma unroll
  for (int d = 0; d < ND; ++d) cv[d] = fb[d * NNN];
#pragma unroll 1
  for (int sel = 0; sel < 3; ++sel) {
    const float* W    = (sel == 0) ? wq : (sel == 1) ? wk : wv;
    const float* bias = (sel == 0) ? bq : (sel == 1) ? bk : bv;
    float acc[16];
#pragma unroll 1
    for (int oi = 0; oi < 16; ++oi) {
      int o = og * 16 + oi;
      const float* wr = W + o * ND;
      float a = bias[o];
#pragma unroll
      for (int d = 0; d < ND; ++d) a += wr[d] * cv[d];
      acc[oi] = a;
    }
    if (sel == 2) {
#pragma unroll
      for (int oi = 0; oi < 16; ++oi)
        vb[(size_t)(b * ND + og * 16 + oi) * NNN + n] = f2b(acc[oi]);
    } else {
      short8 p0, p1;
#pragma unroll
      for (int oi = 0; oi < 8; ++oi) { p0[oi] = (short)f2b(acc[oi]); p1[oi] = (short)f2b(acc[8 + oi]); }
      u16* dst = (sel ? kb : qb) + (size_t)(b * NNN + n) * ND + og * 16;
      *(short8*)dst = p0;
      *(short8*)(dst + 8) = p1;
    }
  }
}

// ---------------- kNN v6 (proven): 8 rows/block, col-halves of 2048,
// float4 loads, lane-leaf tournament with DPP value fold ----------------
__global__ __launch_bounds__(256, 4) void k_knn(const float* __restrict__ f, const float* __restrict__ xx,
                                                int* __restrict__ tidx, float* __restrict__ td2) {
  __shared__ __align__(16) float fm[ND * 8];   // [d][r] row fragments (2 KB)
  __shared__ __align__(16) float sl[4 * 2048]; // 4 rows x 2048 cols (32 KB)
  int t = threadIdx.x;
  int lane = t & 63;
  int w = __builtin_amdgcn_readfirstlane(t >> 6);
  int b = blockIdx.x >> 9;
  int m0 = (blockIdx.x & 511) << 3;
  const float* fb = f + b * ND * NNN;
  { int e = t;       int d = e >> 3, r = e & 7; fm[e] = fb[d * NNN + m0 + r]; }
  { int e = t + 256; int d = e >> 3, r = e & 7; fm[e] = fb[d * NNN + m0 + r]; }
  __syncthreads();
  float lv[2][2];
  int   li[2][2];
#pragma unroll
  for (int h = 0; h < 2; ++h) {
    float acc[64];
#pragma unroll
    for (int i = 0; i < 64; ++i) acc[i] = 0.f;
    for (int d = 0; d < ND; ++d) {
      const float* frow = fb + d * NNN + h * 2048 + 4 * t;
      float4 v0 = *(const float4*)(frow);
      float4 v1 = *(const float4*)(frow + 1024);
      float4 r0 = *(const float4*)&fm[d * 8];
      float4 r1 = *(const float4*)&fm[d * 8 + 4];
      float va0[4] = {v0.x, v0.y, v0.z, v0.w};
      float va1[4] = {v1.x, v1.y, v1.z, v1.w};
      float rr[8]  = {r0.x, r0.y, r0.z, r0.w, r1.x, r1.y, r1.z, r1.w};
#pragma unroll
      for (int c2 = 0; c2 < 4; ++c2)
#pragma unroll
        for (int r = 0; r < 8; ++r) {
          acc[c2 * 8 + r]      += va0[c2] * rr[r];
          acc[32 + c2 * 8 + r] += va1[c2] * rr[r];
        }
    }
    {
      const float* xrow = xx + b * NNN + h * 2048 + 4 * t;
      float4 x0 = *(const float4*)(xrow);
      float4 x1 = *(const float4*)(xrow + 1024);
      float xa0[4] = {x0.x, x0.y, x0.z, x0.w};
      float xa1[4] = {x1.x, x1.y, x1.z, x1.w};
#pragma unroll
      for (int c2 = 0; c2 < 4; ++c2)
#pragma unroll
        for (int r = 0; r < 8; ++r) {
          acc[c2 * 8 + r]      = 2.f * acc[c2 * 8 + r]      - xa0[c2];
          acc[32 + c2 * 8 + r] = 2.f * acc[32 + c2 * 8 + r] - xa1[c2];
        }
    }
#pragma unroll
    for (int s = 0; s < 2; ++s) {
      __syncthreads();
#pragma unroll
      for (int r4 = 0; r4 < 4; ++r4) {
        int r = s * 4 + r4;
#pragma unroll
        for (int jj = 0; jj < 2; ++jj) {
          float4 w4;
          w4.x = acc[jj * 32 + 0 * 8 + r];
          w4.y = acc[jj * 32 + 1 * 8 + r];
          w4.z = acc[jj * 32 + 2 * 8 + r];
          w4.w = acc[jj * 32 + 3 * 8 + r];
          *(float4*)&sl[r4 * 2048 + jj * 1024 + 4 * t] = w4;
        }
      }
      __syncthreads();
      float vals[32];
#pragma unroll
      for (int i = 0; i < 32; ++i) vals[i] = sl[w * 2048 + i * 64 + lane];
      float gv[8]; int gi[8];
#pragma unroll
      for (int g = 0; g < 8; ++g) {
        float v0 = vals[g * 4]; int i0 = (g * 4) * 64 + lane;
#pragma unroll
        for (int k2 = 1; k2 < 4; ++k2)
          pairmax(v0, i0, vals[g * 4 + k2], (g * 4 + k2) * 64 + lane, v0, i0);
        gv[g] = v0; gi[g] = i0;
      }
      float t1v[4]; int t1i[4];
      float t2v[2]; int t2i[2];
      float lvv; int lii;
#pragma unroll
      for (int p = 0; p < 4; ++p) pairmax(gv[2 * p], gi[2 * p], gv[2 * p + 1], gi[2 * p + 1], t1v[p], t1i[p]);
#pragma unroll
      for (int q = 0; q < 2; ++q) pairmax(t1v[2 * q], t1i[2 * q], t1v[2 * q + 1], t1i[2 * q + 1], t2v[q], t2i[q]);
      pairmax(t2v[0], t2i[0], t2v[1], t2i[1], lvv, lii);
      float selv = 0.f; int seli = 0;
#pragma unroll 1
      for (int kx = 0; kx < NK; ++kx) {
        float W = lvv;
        W = fmax_dpp<0xB1>(W);            // quad_perm xor1
        W = fmax_dpp<0x4E>(W);            // quad_perm xor2
        W = fmax_dpp<0x124>(W);           // row_ror:4
        W = fmax_dpp<0x128>(W);           // row_ror:8
        W = fmaxf(W, __shfl_xor(W, 16));
        W = fmaxf(W, __shfl_xor(W, 32));
        unsigned long long mk = __ballot(lvv == W);
        int lw = (int)__ffsll(mk) - 1;
        int wcol = __builtin_amdgcn_readlane(lii, lw);
        if (lane == kx) { selv = W; seli = wcol; }
        int jw = wcol >> 6;
#pragma unroll
        for (int g = 0; g < 8; ++g)
          if (g == (jw >> 2)) {
#pragma unroll
            for (int k2 = 0; k2 < 4; ++k2)
              if (k2 == (jw & 3))
                vals[g * 4 + k2] = (lane == lw) ? -3.0e38f : vals[g * 4 + k2];
            float v0 = vals[g * 4]; int i0 = (g * 4) * 64 + lane;
#pragma unroll
            for (int k2 = 1; k2 < 4; ++k2)
              pairmax(v0, i0, vals[g * 4 + k2], (g * 4 + k2) * 64 + lane, v0, i0);
            gv[g] = v0; gi[g] = i0;
            int p = g >> 1;
            pairmax(gv[2 * p], gi[2 * p], gv[2 * p + 1], gi[2 * p + 1], t1v[p], t1i[p]);
            int q = p >> 1;
            pairmax(t1v[2 * q], t1i[2 * q], t1v[2 * q + 1], t1i[2 * q + 1], t2v[q], t2i[q]);
            pairmax(t2v[0], t2i[0], t2v[1], t2i[1], lvv, lii);
          }
      }
      lv[h][s] = selv; li[h][s] = h * 2048 + seli;
    }
  }
#pragma unroll
  for (int s = 0; s < 2; ++s) {
    int m = m0 + s * 4 + w;
    float xm = xx[b * NNN + m];
    float a   = lv[0][s]; int ai  = li[0][s];
    float bb2 = lv[1][s]; int bi2 = li[1][s];
    int cntB = 0, cntA = 0;
#pragma unroll
    for (int j = 0; j < 16; ++j) {
      float bj = __shfl(bb2, j);
      cntB += (bj > a) ? 1 : 0;
      float aj = __shfl(a, j);
      cntA += (aj >= bb2) ? 1 : 0;
    }
    if (lane < 16) {
      int base = (b * NNN + m) * NK;
      int rA = lane + cntB;
      int rB = lane + cntA;
      if (rA < NK) {
        float dd = xm - a;
        tidx[base + rA] = ai;
        td2[base + rA] = dd > 0.f ? dd : 0.f;
      }
      if (rB < NK) {
        float dd = xm - bb2;
        tidx[base + rB] = bi2;
        td2[base + rB] = dd > 0.f ? dd : 0.f;
      }
    }
  }
}

// ---------------- attention v2: 32 q-rows/block (K/V loaded once per 2 row-tiles) ----------------
__global__ __launch_bounds__(256) void k_attn(const u16* __restrict__ qb,
                                              const u16* __restrict__ kb,
                                              const u16* __restrict__ vb,
                                              float* __restrict__ fgt,
                                              float* __restrict__ linv) {
  __shared__ __align__(16) u16 P[32 * 520];   // 33.3 KB
  __shared__ float rsum[4][32];
  int t = threadIdx.x;
  int lane = t & 63;
  int w = __builtin_amdgcn_readfirstlane(t >> 6);
  int quad = lane >> 4;
  int l15 = lane & 15;
  int b = blockIdx.x >> 7;
  int m0 = (blockIdx.x & 127) << 5;
  const u16* qra = qb + (size_t)(b * NNN + m0 + l15) * ND + quad * 8;
  const u16* qrb = qb + (size_t)(b * NNN + m0 + 16 + l15) * ND + quad * 8;
  short8 qa0a = *(const short8*)(qra), qa1a = *(const short8*)(qra + 32);
  short8 qa0b = *(const short8*)(qrb), qa1b = *(const short8*)(qrb + 32);
  const u16* kbase = kb + (size_t)b * NNN * ND;
  const u16* vrow  = vb + (size_t)(b * ND + w * 16 + l15) * NNN;
  floatx4 c2a = {0.f, 0.f, 0.f, 0.f};
  floatx4 c2b = {0.f, 0.f, 0.f, 0.f};
  float rsa[4] = {0.f, 0.f, 0.f, 0.f};
  float rsb[4] = {0.f, 0.f, 0.f, 0.f};
#pragma unroll 1
  for (int it = 0; it < 8; ++it) {
    int nchunk = it * 512;
#pragma unroll 1
    for (int ct = 0; ct < 8; ++ct) {
      int cc0 = (w * 8 + ct) * 16;
      const u16* krow = kbase + (size_t)(nchunk + cc0 + l15) * ND + quad * 8;
      short8 kf0 = *(const short8*)(krow);
      short8 kf1 = *(const short8*)(krow + 32);
      floatx4 acca = {0.f, 0.f, 0.f, 0.f};
      acca = __builtin_amdgcn_mfma_f32_16x16x32_bf16(qa0a, kf0, acca, 0, 0, 0);
      acca = __builtin_amdgcn_mfma_f32_16x16x32_bf16(qa1a, kf1, acca, 0, 0, 0);
      floatx4 accb = {0.f, 0.f, 0.f, 0.f};
      accb = __builtin_amdgcn_mfma_f32_16x16x32_bf16(qa0b, kf0, accb, 0, 0, 0);
      accb = __builtin_amdgcn_mfma_f32_16x16x32_bf16(qa1b, kf1, accb, 0, 0, 0);
      int ccol = cc0 + l15;
#pragma unroll
      for (int r = 0; r < 4; ++r) {
        float ea = __expf(acca[r] * 0.125f);
        rsa[r] += ea;
        P[(quad * 4 + r) * 520 + ccol] = f2b(ea);
        float eb = __expf(accb[r] * 0.125f);
        rsb[r] += eb;
        P[(16 + quad * 4 + r) * 520 + ccol] = f2b(eb);
      }
    }
    __syncthreads();
    const u16* vp = vrow + nchunk + quad * 8;
#pragma unroll
    for (int kk = 0; kk < 16; ++kk) {
      short8 b2 = *(const short8*)(vp + kk * 32);
      short8 a2a = *(const short8*)&P[l15 * 520 + kk * 32 + quad * 8];
      short8 a2b = *(const short8*)&P[(16 + l15) * 520 + kk * 32 + quad * 8];
      c2a = __builtin_amdgcn_mfma_f32_16x16x32_bf16(a2a, b2, c2a, 0, 0, 0);
      c2b = __builtin_amdgcn_mfma_f32_16x16x32_bf16(a2b, b2, c2b, 0, 0, 0);
    }
    __syncthreads();
  }
#pragma unroll
  for (int r = 0; r < 4; ++r) {
    float va = rsa[r];
    va += __shfl_xor(va, 1); va += __shfl_xor(va, 2);
    va += __shfl_xor(va, 4); va += __shfl_xor(va, 8);
    rsa[r] = va;
    float vb2 = rsb[r];
    vb2 += __shfl_xor(vb2, 1); vb2 += __shfl_xor(vb2, 2);
    vb2 += __shfl_xor(vb2, 4); vb2 += __shfl_xor(vb2, 8);
    rsb[r] = vb2;
  }
  if (l15 == 0) {
#pragma unroll
    for (int r = 0; r < 4; ++r) {
      rsum[w][quad * 4 + r] = rsa[r];
      rsum[w][16 + quad * 4 + r] = rsb[r];
    }
  }
#pragma unroll
  for (int r = 0; r < 4; ++r) {
    fgt[(size_t)(b * NNN + m0 + quad * 4 + r) * ND + w * 16 + l15] = c2a[r];
    fgt[(size_t)(b * NNN + m0 + 16 + quad * 4 + r) * ND + w * 16 + l15] = c2b[r];
  }
  __syncthreads();
  if (t < 32) {
    float s = rsum[0][t] + rsum[1][t] + rsum[2][t] + rsum[3][t];
    linv[b * NNN + m0 + t] = 1.f / s;
  }
}

// ---------------- A/B2 pre-GEMMs: fp32 compute, bf16 store [b][n][o] ----------------
__global__ __launch_bounds__(256) void k_ab(const float* __restrict__ f, const float* __restrict__ wl,
                                            u16* __restrict__ Apre, u16* __restrict__ Bpre) {
  __shared__ float fl[ND * 64];
  int t = threadIdx.x;
  int b = blockIdx.x >> 6;
  int n0 = (blockIdx.x & 63) << 6;
  for (int e = t; e < ND * 64; e += 256) {
    int d = e >> 6, c = e & 63;
    fl[e] = f[b * ND * NNN + d * NNN + n0 + c];
  }
  __syncthreads();
  int lane = t & 63;
  int w = __builtin_amdgcn_readfirstlane(t >> 6);
#pragma unroll 1
  for (int g = 0; g < 8; ++g) {
    float acc[8] = {0, 0, 0, 0, 0, 0, 0, 0};
    int p0 = w * 64 + g * 8;
    for (int d = 0; d < ND; ++d) {
      float fv = fl[d * 64 + lane];
#pragma unroll
      for (int u = 0; u < 8; ++u) {
        int p = p0 + u;
        int o = p & 127, sel = p >> 7;
        acc[u] += wl[o * 129 + sel * 64 + d] * fv;
      }
    }
#pragma unroll
    for (int u = 0; u < 8; ++u) {
      int p = p0 + u;
      int o = p & 127, sel = p >> 7;
      u16* outp = sel ? Bpre : Apre;
      outp[(size_t)(b * NNN + n0 + lane) * NO + o] = f2b(acc[u]);
    }
  }
}

// ---------------- intra: bf16 A/B2 gathers; max/min over k + fused stats ----------------
__global__ __launch_bounds__(128) void k_intra(const u16* __restrict__ Apre, const u16* __restrict__ Bpre,
                                               const int* __restrict__ tidx, const float* __restrict__ td2,
                                               const float* __restrict__ wl, float* __restrict__ imax,
                                               float* __restrict__ imin, float* __restrict__ stats) {
  __shared__ int sidx[32 * NK];
  __shared__ float sdst[32 * NK];
  int t = threadIdx.x;
  int b = blockIdx.x >> 7;
  int n0 = (blockIdx.x & 127) << 5;
  for (int e = t; e < 32 * NK; e += 128) {
    int base = (b * NNN + n0 + (e >> 4)) * NK + (e & 15);
    sidx[e] = tidx[base];
    sdst[e] = sqrtf(td2[base]);
  }
  __syncthreads();
  int o = t;
  float w128 = wl[o * 129 + 128];
  float ssum = 0.f, ssq = 0.f;
  for (int c = 0; c < 32; ++c) {
    float a = b2f(Apre[(size_t)(b * NNN + n0 + c) * NO + o]);
    float mx = -3.4e38f, mn = 3.4e38f;
#pragma unroll
    for (int kx = 0; kx < NK; ++kx) {
      int id = sidx[c * NK + kx];
      float y = a + b2f(Bpre[(size_t)(b * NNN + id) * NO + o]) + w128 * sdst[c * NK + kx];
      mx = fmaxf(mx, y); mn = fminf(mn, y);
      ssum += y; ssq += y * y;
    }
    imax[(b * NO + o) * NNN + n0 + c] = mx;
    imin[(b * NO + o) * NNN + n0 + c] = mn;
  }
  atomicAdd(&stats[o], ssum);
  atomicAdd(&stats[NO + o], ssq);
}

// ---------------- sem: z = w_sem * (fgt * linv) -> [b][o][n] + fused stats ----------------
__global__ __launch_bounds__(256) void k_sem(const float* __restrict__ fgt, const float* __restrict__ linv,
                                             const float* __restrict__ wsem, float* __restrict__ zsem,
                                             float* __restrict__ sout) {
  __shared__ float fl[64 * 65];
  int t = threadIdx.x;
  int b = blockIdx.x >> 6;
  int n0 = (blockIdx.x & 63) << 6;
  for (int e = t; e < 64 * 64; e += 256) {
    int n = e >> 6, d = e & 63;
    fl[n * 65 + d] = fgt[(size_t)(b * NNN + n0 + n) * ND + d] * linv[b * NNN + n0 + n];
  }
  __syncthreads();
  int lane = t & 63;
  int ob = __builtin_amdgcn_readfirstlane((t >> 6) * 32);
#pragma unroll 1
  for (int g = 0; g < 4; ++g) {
    float acc[8] = {0, 0, 0, 0, 0, 0, 0, 0};
    for (int d = 0; d < ND; ++d) {
      float fv = fl[lane * 65 + d];
#pragma unroll
      for (int u = 0; u < 8; ++u) acc[u] += wsem[(ob + g * 8 + u) * ND + d] * fv;
    }
#pragma unroll
    for (int u = 0; u < 8; ++u) {
      int o = ob + g * 8 + u;
      zsem[(b * NO + o) * NNN + n0 + lane] = acc[u];
      float s = acc[u], q = acc[u] * acc[u];
#pragma unroll
      for (int off = 1; off < 64; off <<= 1) { s += __shfl_xor(s, off); q += __shfl_xor(q, off); }
      if (lane == 0) { atomicAdd(&sout[o], s); atomicAdd(&sout[NO + o], q); }
    }
  }
}

// ---------------- finalize BN: merged intra+sem (256 threads) ----------------
__global__ void k_fin2(const float* __restrict__ stats,
                       const float* __restrict__ g1, const float* __restrict__ be1, float ci1,
                       const float* __restrict__ g2, const float* __restrict__ be2, float ci2,
                       float* __restrict__ coef) {
  int t = threadIdx.x;
  int o = t & 127;
  int which = t >> 7;
  const float* st = stats + which * 2 * NO;
  const float* g  = which ? g2 : g1;
  const float* be = which ? be2 : be1;
  float ci = which ? ci2 : ci1;
  float mean = st[o] * ci;
  float var = st[NO + o] * ci - mean * mean;
  var = var > 0.f ? var : 0.f;
  float a = g[o] * rsqrtf(var + BN_EPS);
  coef[which * 2 * NO + o] = a;
  coef[which * 2 * NO + NO + o] = be[o] - mean * a;
}

// ---------------- finalize BN single (for full) ----------------
__global__ void k_fin(const float* __restrict__ stats, const float* __restrict__ g,
                      const float* __restrict__ be, float cnt_inv, float* __restrict__ coef) {
  int o = threadIdx.x;
  float mean = stats[o] * cnt_inv;
  float var = stats[NO + o] * cnt_inv - mean * mean;
  var = var > 0.f ? var : 0.f;
  float a = g[o] * rsqrtf(var + BN_EPS);
  coef[o] = a;
  coef[NO + o] = be[o] - mean * a;
}

// ---------------- full: z = w_full * lrelu(BN(cat)) + fused stats ----------------
__global__ __launch_bounds__(256) void k_full(const float* __restrict__ imax, const float* __restrict__ imin,
                                              const float* __restrict__ zsem, const float* __restrict__ wfull,
                                              const float* __restrict__ coef, float* __restrict__ zfull,
                                              float* __restrict__ sout) {
  __shared__ float fl[2 * NO * 64];
  int t = threadIdx.x;
  int b = blockIdx.x >> 6;
  int n0 = (blockIdx.x & 63) << 6;
  for (int e = t; e < 2 * NO * 64; e += 256) {
    int c = e >> 6, col = e & 63;
    float aa, bb, x;
    if (c < NO) {
      aa = coef[c]; bb = coef[NO + c];
      const float* src = (aa >= 0.f) ? imax : imin;
      x = src[(b * NO + c) * NNN + n0 + col];
    } else {
      int c2 = c - NO;
      aa = coef[2 * NO + c2]; bb = coef[3 * NO + c2];
      x = zsem[(b * NO + c2) * NNN + n0 + col];
    }
    float y = aa * x + bb;
    fl[e] = (y >= 0.f) ? y : NEG * y;
  }
  __syncthreads();
  int lane = t & 63;
  int ob = __builtin_amdgcn_readfirstlane((t >> 6) * 32);
#pragma unroll 1
  for (int g = 0; g < 4; ++g) {
    float acc[8] = {0, 0, 0, 0, 0, 0, 0, 0};
    for (int c = 0; c < 2 * NO; ++c) {
      float fv = fl[c * 64 + lane];
#pragma unroll
      for (int u = 0; u < 8; ++u) acc[u] += wfull[(ob + g * 8 + u) * (2 * NO) + c] * fv;
    }
#pragma unroll
    for (int u = 0; u < 8; ++u) {
      int o = ob + g * 8 + u;
      zfull[(b * NO + o) * NNN + n0 + lane] = acc[u];
      float s = acc[u], q = acc[u] * acc[u];
#pragma unroll
      for (int off = 1; off < 64; off <<= 1) { s += __shfl_xor(s, off); q += __shfl_xor(q, off); }
      if (lane == 0) { atomicAdd(&sout[o], s); atomicAdd(&sout[NO + o], q); }
    }
  }
}

// ---------------- out = lrelu(a*z + b) ----------------
__global__ void k_out(const float* __restrict__ zfull, const float* __restrict__ coef,
                      float* __restrict__ out) {
  int gid = blockIdx.x * 256 + threadIdx.x;
  int o = (gid >> 12) & 127;
  float y = coef[o] * zfull[gid] + coef[NO + o];
  out[gid] = (y >= 0.f) ? y : NEG * y;
}

extern "C" void kernel_launch(void* const* d_in, const int* in_sizes, int n_in,
                              void* d_out, int out_size, void* d_ws, size_t ws_size,
                              hipStream_t stream) {
  (void)in_sizes; (void)n_in; (void)out_size; (void)ws_size;
  const float* f       = (const float*)d_in[0];
  const float* w_local = (const float*)d_in[1];
  const float* g_local = (const float*)d_in[2];
  const float* b_local = (const float*)d_in[3];
  const float* w_sem   = (const float*)d_in[4];
  const float* g_sem   = (const float*)d_in[5];
  const float* b_sem   = (const float*)d_in[6];
  const float* w_full  = (const float*)d_in[7];
  const float* g_full  = (const float*)d_in[8];
  const float* b_full  = (const float*)d_in[9];
  const float* wq = (const float*)d_in[10];
  const float* bq = (const float*)d_in[11];
  const float* wk = (const float*)d_in[12];
  const float* bk = (const float*)d_in[13];
  const float* wv = (const float*)d_in[14];
  const float* bv = (const float*)d_in[15];
  float* Wp = (float*)d_ws;
  u16* qb16 = (u16*)(Wp + OFF_Q);
  u16* kb16 = (u16*)(Wp + OFF_K);
  u16* vb16 = (u16*)(Wp + OFF_V);
  u16* ap16 = (u16*)(Wp + OFF_APRE);
  u16* bp16 = (u16*)(Wp + OFF_BPRE);

  hipMemsetAsync(Wp + OFF_STATS, 0, 6 * NO * sizeof(float), stream);  // intra+sem+full stats
  k_xx  <<<NB * NNN / 256, 256, 0, stream>>>(f, Wp + OFF_XX);
  k_qkv <<<NB * NNN / 64, 256, 0, stream>>>(f, wq, bq, wk, bk, wv, bv, qb16, kb16, vb16);
  k_knn <<<NB * (NNN / 8), 256, 0, stream>>>(f, Wp + OFF_XX, (int*)(Wp + OFF_IDX), Wp + OFF_D2);
  k_attn<<<NB * (NNN / 32), 256, 0, stream>>>(qb16, kb16, vb16, Wp + OFF_FGT, Wp + OFF_LINV);
  k_ab  <<<NB * (NNN / 64), 256, 0, stream>>>(f, w_local, ap16, bp16);
  k_intra<<<NB * (NNN / 32), 128, 0, stream>>>(ap16, bp16,
                                               (const int*)(Wp + OFF_IDX), Wp + OFF_D2,
                                               w_local, Wp + OFF_IMAX, Wp + OFF_IMIN, Wp + OFF_STATS);
  k_sem <<<NB * (NNN / 64), 256, 0, stream>>>(Wp + OFF_FGT, Wp + OFF_LINV, w_sem, Wp + OFF_ZSEM,
                                              Wp + OFF_STATS + 2 * NO);
  k_fin2<<<1, 2 * NO, 0, stream>>>(Wp + OFF_STATS,
                                   g_local, b_local, 1.f / (float)(NB * NNN * NK),
                                   g_sem, b_sem, 1.f / (float)(NB * NNN),
                                   Wp + OFF_COEF);
  k_full<<<NB * (NNN / 64), 256, 0, stream>>>(Wp + OFF_IMAX, Wp + OFF_IMIN, Wp + OFF_ZSEM,
                                              w_full, Wp + OFF_COEF, Wp + OFF_ZFULL,
                                              Wp + OFF_STATS + 4 * NO);
  k_fin <<<1, NO, 0, stream>>>(Wp + OFF_STATS + 4 * NO, g_full, b_full,
                               1.f / (float)(NB * NNN), Wp + OFF_COEF + 4 * NO);
  k_out <<<NB * NO * NNN / 256, 256, 0, stream>>>(Wp + OFF_ZFULL, Wp + OFF_COEF + 4 * NO,
                                                  (float*)d_out);
}

// Round 12
// 632.215 us; speedup vs baseline: 1.2236x; 1.2236x over previous
//
#include <hip/hip_runtime.h>
#include <math.h>

constexpr int NB = 4;      // batch
constexpr int ND = 64;     // feature dim
constexpr int NNN = 4096;  // points
constexpr int NO = 128;    // out channels
constexpr int NK = 16;     // k-nn
constexpr float NEG = 0.01f;
constexpr float BN_EPS = 1e-5f;

typedef unsigned short u16;
typedef unsigned int u32;
typedef __attribute__((ext_vector_type(8))) short short8;
typedef __attribute__((ext_vector_type(4))) float floatx4;

// workspace offsets (in floats)
constexpr int OFF_XX    = 0;
constexpr int OFF_IDX   = 16384;
constexpr int OFF_D2    = 278528;
constexpr int OFF_Q     = 540672;       // qb16 bf16 [b][n][d]
constexpr int OFF_K     = 1589248;      // kb16 bf16 [b][n][d]
constexpr int OFF_V     = 2637824;      // vb16 bf16 [b][d][n]
constexpr int OFF_FGT   = 3686400;      // fgt fp32 [b][n][d] (unnormalized)
constexpr int OFF_APRE  = 4734976;      // bf16 [b][n][o]
constexpr int OFF_BPRE  = 6832128;      // bf16 [b][n][o]
constexpr int OFF_IMAX  = 8929280;
constexpr int OFF_IMIN  = 11026432;
constexpr int OFF_ZSEM  = OFF_Q;
constexpr int OFF_ZFULL = OFF_V;
constexpr int OFF_STATS = 13123584;     // 6*NO
constexpr int OFF_COEF  = 13124352;
constexpr int OFF_LINV  = 13125120;

__device__ __forceinline__ u16 f2b(float x) {       // fp32 -> bf16 RNE
  u32 u = __builtin_bit_cast(u32, x);
  u += 0x7fffu + ((u >> 16) & 1u);
  return (u16)(u >> 16);
}
__device__ __forceinline__ float b2f(u16 h) {
  u32 u = (u32)h << 16;
  return __builtin_bit_cast(float, u);
}

// value-only max fold step via DPP (single v_max_f32 with fused DPP src)
template <int CTRL>
__device__ __forceinline__ float fmax_dpp(float v) {
  int b = __builtin_bit_cast(int, v);
  int s = __builtin_amdgcn_update_dpp(b, b, CTRL, 0xF, 0xF, false);
  return fmaxf(v, __builtin_bit_cast(float, s));
}
// (value,col) pair fold: larger value wins; tie -> keep left (smaller col by construction)
__device__ __forceinline__ void pairmax(float av, int ai, float bv, int bi, float& rv, int& ri) {
  bool tk = bv > av;
  rv = tk ? bv : av;
  ri = tk ? bi : ai;
}

// ---------------- xx[b][n] = sum_d f^2 ----------------
__global__ void k_xx(const float* __restrict__ f, float* __restrict__ xx) {
  int gid = blockIdx.x * 256 + threadIdx.x;
  int b = gid >> 12, n = gid & 4095;
  const float* fb = f + b * ND * NNN + n;
  float s = 0.f;
#pragma unroll
  for (int d = 0; d < ND; ++d) { float v = fb[d * NNN]; s += v * v; }
  xx[gid] = s;
}

// ---------------- q/k/v = W f + bias -> bf16 (grid.y selects; 768 blocks) ----------------
__global__ __launch_bounds__(256) void k_qkv(const float* __restrict__ f,
    const float* __restrict__ wq, const float* __restrict__ bq,
    const float* __restrict__ wk, const float* __restrict__ bk,
    const float* __restrict__ wv, const float* __restrict__ bv,
    u16* __restrict__ qb, u16* __restrict__ kb, u16* __restrict__ vb) {
  int sel = blockIdx.y;
  const float* W    = (sel == 0) ? wq : (sel == 1) ? wk : wv;
  const float* bias = (sel == 0) ? bq : (sel == 1) ? bk : bv;
  int t = threadIdx.x;
  int lane = t & 63;
  int og = __builtin_amdgcn_readfirstlane(t >> 6);
  int gcol = blockIdx.x * 64 + lane;
  int b = gcol >> 12, n = gcol & 4095;
  const float* fb = f + b * ND * NNN + n;
  float cv[64];
#pragma unroll
  for (int d = 0; d < ND; ++d) cv[d] = fb[d * NNN];
  float acc[16];
#pragma unroll 1
  for (int oi = 0; oi < 16; ++oi) {
    int o = og * 16 + oi;
    const float* wr = W + o * ND;
    float a = bias[o];
#pragma unroll
    for (int d = 0; d < ND; ++d) a += wr[d] * cv[d];
    acc[oi] = a;
  }
  if (sel == 2) {
#pragma unroll
    for (int oi = 0; oi < 16; ++oi)
      vb[(size_t)(b * ND + og * 16 + oi) * NNN + n] = f2b(acc[oi]);
  } else {
    short8 p0, p1;
#pragma unroll
    for (int oi = 0; oi < 8; ++oi) { p0[oi] = (short)f2b(acc[oi]); p1[oi] = (short)f2b(acc[8 + oi]); }
    u16* dst = (sel ? kb : qb) + (size_t)(b * NNN + n) * ND + og * 16;
    *(short8*)dst = p0;
    *(short8*)(dst + 8) = p1;
  }
}

// ---------------- kNN v6 (proven): 8 rows/block, col-halves of 2048,
// float4 loads, lane-leaf tournament with DPP value fold ----------------
__global__ __launch_bounds__(256, 4) void k_knn(const float* __restrict__ f, const float* __restrict__ xx,
                                                int* __restrict__ tidx, float* __restrict__ td2) {
  __shared__ __align__(16) float fm[ND * 8];   // [d][r] row fragments (2 KB)
  __shared__ __align__(16) float sl[4 * 2048]; // 4 rows x 2048 cols (32 KB)
  int t = threadIdx.x;
  int lane = t & 63;
  int w = __builtin_amdgcn_readfirstlane(t >> 6);
  int b = blockIdx.x >> 9;
  int m0 = (blockIdx.x & 511) << 3;
  const float* fb = f + b * ND * NNN;
  { int e = t;       int d = e >> 3, r = e & 7; fm[e] = fb[d * NNN + m0 + r]; }
  { int e = t + 256; int d = e >> 3, r = e & 7; fm[e] = fb[d * NNN + m0 + r]; }
  __syncthreads();
  float lv[2][2];
  int   li[2][2];
#pragma unroll
  for (int h = 0; h < 2; ++h) {
    float acc[64];
#pragma unroll
    for (int i = 0; i < 64; ++i) acc[i] = 0.f;
    for (int d = 0; d < ND; ++d) {
      const float* frow = fb + d * NNN + h * 2048 + 4 * t;
      float4 v0 = *(const float4*)(frow);
      float4 v1 = *(const float4*)(frow + 1024);
      float4 r0 = *(const float4*)&fm[d * 8];
      float4 r1 = *(const float4*)&fm[d * 8 + 4];
      float va0[4] = {v0.x, v0.y, v0.z, v0.w};
      float va1[4] = {v1.x, v1.y, v1.z, v1.w};
      float rr[8]  = {r0.x, r0.y, r0.z, r0.w, r1.x, r1.y, r1.z, r1.w};
#pragma unroll
      for (int c2 = 0; c2 < 4; ++c2)
#pragma unroll
        for (int r = 0; r < 8; ++r) {
          acc[c2 * 8 + r]      += va0[c2] * rr[r];
          acc[32 + c2 * 8 + r] += va1[c2] * rr[r];
        }
    }
    {
      const float* xrow = xx + b * NNN + h * 2048 + 4 * t;
      float4 x0 = *(const float4*)(xrow);
      float4 x1 = *(const float4*)(xrow + 1024);
      float xa0[4] = {x0.x, x0.y, x0.z, x0.w};
      float xa1[4] = {x1.x, x1.y, x1.z, x1.w};
#pragma unroll
      for (int c2 = 0; c2 < 4; ++c2)
#pragma unroll
        for (int r = 0; r < 8; ++r) {
          acc[c2 * 8 + r]      = 2.f * acc[c2 * 8 + r]      - xa0[c2];
          acc[32 + c2 * 8 + r] = 2.f * acc[32 + c2 * 8 + r] - xa1[c2];
        }
    }
#pragma unroll
    for (int s = 0; s < 2; ++s) {
      __syncthreads();
#pragma unroll
      for (int r4 = 0; r4 < 4; ++r4) {
        int r = s * 4 + r4;
#pragma unroll
        for (int jj = 0; jj < 2; ++jj) {
          float4 w4;
          w4.x = acc[jj * 32 + 0 * 8 + r];
          w4.y = acc[jj * 32 + 1 * 8 + r];
          w4.z = acc[jj * 32 + 2 * 8 + r];
          w4.w = acc[jj * 32 + 3 * 8 + r];
          *(float4*)&sl[r4 * 2048 + jj * 1024 + 4 * t] = w4;
        }
      }
      __syncthreads();
      float vals[32];
#pragma unroll
      for (int i = 0; i < 32; ++i) vals[i] = sl[w * 2048 + i * 64 + lane];
      float gv[8]; int gi[8];
#pragma unroll
      for (int g = 0; g < 8; ++g) {
        float v0 = vals[g * 4]; int i0 = (g * 4) * 64 + lane;
#pragma unroll
        for (int k2 = 1; k2 < 4; ++k2)
          pairmax(v0, i0, vals[g * 4 + k2], (g * 4 + k2) * 64 + lane, v0, i0);
        gv[g] = v0; gi[g] = i0;
      }
      float t1v[4]; int t1i[4];
      float t2v[2]; int t2i[2];
      float lvv; int lii;
#pragma unroll
      for (int p = 0; p < 4; ++p) pairmax(gv[2 * p], gi[2 * p], gv[2 * p + 1], gi[2 * p + 1], t1v[p], t1i[p]);
#pragma unroll
      for (int q = 0; q < 2; ++q) pairmax(t1v[2 * q], t1i[2 * q], t1v[2 * q + 1], t1i[2 * q + 1], t2v[q], t2i[q]);
      pairmax(t2v[0], t2i[0], t2v[1], t2i[1], lvv, lii);
      float selv = 0.f; int seli = 0;
#pragma unroll 1
      for (int kx = 0; kx < NK; ++kx) {
        float W = lvv;
        W = fmax_dpp<0xB1>(W);            // quad_perm xor1
        W = fmax_dpp<0x4E>(W);            // quad_perm xor2
        W = fmax_dpp<0x124>(W);           // row_ror:4
        W = fmax_dpp<0x128>(W);           // row_ror:8
        W = fmaxf(W, __shfl_xor(W, 16));
        W = fmaxf(W, __shfl_xor(W, 32));
        unsigned long long mk = __ballot(lvv == W);
        int lw = (int)__ffsll(mk) - 1;
        int wcol = __builtin_amdgcn_readlane(lii, lw);
        if (lane == kx) { selv = W; seli = wcol; }
        int jw = wcol >> 6;
#pragma unroll
        for (int g = 0; g < 8; ++g)
          if (g == (jw >> 2)) {
#pragma unroll
            for (int k2 = 0; k2 < 4; ++k2)
              if (k2 == (jw & 3))
                vals[g * 4 + k2] = (lane == lw) ? -3.0e38f : vals[g * 4 + k2];
            float v0 = vals[g * 4]; int i0 = (g * 4) * 64 + lane;
#pragma unroll
            for (int k2 = 1; k2 < 4; ++k2)
              pairmax(v0, i0, vals[g * 4 + k2], (g * 4 + k2) * 64 + lane, v0, i0);
            gv[g] = v0; gi[g] = i0;
            int p = g >> 1;
            pairmax(gv[2 * p], gi[2 * p], gv[2 * p + 1], gi[2 * p + 1], t1v[p], t1i[p]);
            int q = p >> 1;
            pairmax(t1v[2 * q], t1i[2 * q], t1v[2 * q + 1], t1i[2 * q + 1], t2v[q], t2i[q]);
            pairmax(t2v[0], t2i[0], t2v[1], t2i[1], lvv, lii);
          }
      }
      lv[h][s] = selv; li[h][s] = h * 2048 + seli;
    }
  }
#pragma unroll
  for (int s = 0; s < 2; ++s) {
    int m = m0 + s * 4 + w;
    float xm = xx[b * NNN + m];
    float a   = lv[0][s]; int ai  = li[0][s];
    float bb2 = lv[1][s]; int bi2 = li[1][s];
    int cntB = 0, cntA = 0;
#pragma unroll
    for (int j = 0; j < 16; ++j) {
      float bj = __shfl(bb2, j);
      cntB += (bj > a) ? 1 : 0;
      float aj = __shfl(a, j);
      cntA += (aj >= bb2) ? 1 : 0;
    }
    if (lane < 16) {
      int base = (b * NNN + m) * NK;
      int rA = lane + cntB;
      int rB = lane + cntA;
      if (rA < NK) {
        float dd = xm - a;
        tidx[base + rA] = ai;
        td2[base + rA] = dd > 0.f ? dd : 0.f;
      }
      if (rB < NK) {
        float dd = xm - bb2;
        tidx[base + rB] = bi2;
        td2[base + rB] = dd > 0.f ? dd : 0.f;
      }
    }
  }
}

// ---------------- attention v2: 32 q-rows/block (K/V loaded once per 2 row-tiles) ----------------
__global__ __launch_bounds__(256) void k_attn(const u16* __restrict__ qb,
                                              const u16* __restrict__ kb,
                                              const u16* __restrict__ vb,
                                              float* __restrict__ fgt,
                                              float* __restrict__ linv) {
  __shared__ __align__(16) u16 P[32 * 520];   // 33.3 KB
  __shared__ float rsum[4][32];
  int t = threadIdx.x;
  int lane = t & 63;
  int w = __builtin_amdgcn_readfirstlane(t >> 6);
  int quad = lane >> 4;
  int l15 = lane & 15;
  int b = blockIdx.x >> 7;
  int m0 = (blockIdx.x & 127) << 5;
  const u16* qra = qb + (size_t)(b * NNN + m0 + l15) * ND + quad * 8;
  const u16* qrb = qb + (size_t)(b * NNN + m0 + 16 + l15) * ND + quad * 8;
  short8 qa0a = *(const short8*)(qra), qa1a = *(const short8*)(qra + 32);
  short8 qa0b = *(const short8*)(qrb), qa1b = *(const short8*)(qrb + 32);
  const u16* kbase = kb + (size_t)b * NNN * ND;
  const u16* vrow  = vb + (size_t)(b * ND + w * 16 + l15) * NNN;
  floatx4 c2a = {0.f, 0.f, 0.f, 0.f};
  floatx4 c2b = {0.f, 0.f, 0.f, 0.f};
  float rsa[4] = {0.f, 0.f, 0.f, 0.f};
  float rsb[4] = {0.f, 0.f, 0.f, 0.f};
#pragma unroll 1
  for (int it = 0; it < 8; ++it) {
    int nchunk = it * 512;
#pragma unroll 1
    for (int ct = 0; ct < 8; ++ct) {
      int cc0 = (w * 8 + ct) * 16;
      const u16* krow = kbase + (size_t)(nchunk + cc0 + l15) * ND + quad * 8;
      short8 kf0 = *(const short8*)(krow);
      short8 kf1 = *(const short8*)(krow + 32);
      floatx4 acca = {0.f, 0.f, 0.f, 0.f};
      acca = __builtin_amdgcn_mfma_f32_16x16x32_bf16(qa0a, kf0, acca, 0, 0, 0);
      acca = __builtin_amdgcn_mfma_f32_16x16x32_bf16(qa1a, kf1, acca, 0, 0, 0);
      floatx4 accb = {0.f, 0.f, 0.f, 0.f};
      accb = __builtin_amdgcn_mfma_f32_16x16x32_bf16(qa0b, kf0, accb, 0, 0, 0);
      accb = __builtin_amdgcn_mfma_f32_16x16x32_bf16(qa1b, kf1, accb, 0, 0, 0);
      int ccol = cc0 + l15;
#pragma unroll
      for (int r = 0; r < 4; ++r) {
        float ea = __expf(acca[r] * 0.125f);
        rsa[r] += ea;
        P[(quad * 4 + r) * 520 + ccol] = f2b(ea);
        float eb = __expf(accb[r] * 0.125f);
        rsb[r] += eb;
        P[(16 + quad * 4 + r) * 520 + ccol] = f2b(eb);
      }
    }
    __syncthreads();
    const u16* vp = vrow + nchunk + quad * 8;
#pragma unroll
    for (int kk = 0; kk < 16; ++kk) {
      short8 b2 = *(const short8*)(vp + kk * 32);
      short8 a2a = *(const short8*)&P[l15 * 520 + kk * 32 + quad * 8];
      short8 a2b = *(const short8*)&P[(16 + l15) * 520 + kk * 32 + quad * 8];
      c2a = __builtin_amdgcn_mfma_f32_16x16x32_bf16(a2a, b2, c2a, 0, 0, 0);
      c2b = __builtin_amdgcn_mfma_f32_16x16x32_bf16(a2b, b2, c2b, 0, 0, 0);
    }
    __syncthreads();
  }
#pragma unroll
  for (int r = 0; r < 4; ++r) {
    float va = rsa[r];
    va += __shfl_xor(va, 1); va += __shfl_xor(va, 2);
    va += __shfl_xor(va, 4); va += __shfl_xor(va, 8);
    rsa[r] = va;
    float vb2 = rsb[r];
    vb2 += __shfl_xor(vb2, 1); vb2 += __shfl_xor(vb2, 2);
    vb2 += __shfl_xor(vb2, 4); vb2 += __shfl_xor(vb2, 8);
    rsb[r] = vb2;
  }
  if (l15 == 0) {
#pragma unroll
    for (int r = 0; r < 4; ++r) {
      rsum[w][quad * 4 + r] = rsa[r];
      rsum[w][16 + quad * 4 + r] = rsb[r];
    }
  }
#pragma unroll
  for (int r = 0; r < 4; ++r) {
    fgt[(size_t)(b * NNN + m0 + quad * 4 + r) * ND + w * 16 + l15] = c2a[r];
    fgt[(size_t)(b * NNN + m0 + 16 + quad * 4 + r) * ND + w * 16 + l15] = c2b[r];
  }
  __syncthreads();
  if (t < 32) {
    float s = rsum[0][t] + rsum[1][t] + rsum[2][t] + rsum[3][t];
    linv[b * NNN + m0 + t] = 1.f / s;
  }
}

// ---------------- A/B2 pre-GEMMs: fp32 compute, bf16 store [b][n][o] ----------------
__global__ __launch_bounds__(256) void k_ab(const float* __restrict__ f, const float* __restrict__ wl,
                                            u16* __restrict__ Apre, u16* __restrict__ Bpre) {
  __shared__ float fl[ND * 64];
  int t = threadIdx.x;
  int b = blockIdx.x >> 6;
  int n0 = (blockIdx.x & 63) << 6;
  for (int e = t; e < ND * 64; e += 256) {
    int d = e >> 6, c = e & 63;
    fl[e] = f[b * ND * NNN + d * NNN + n0 + c];
  }
  __syncthreads();
  int lane = t & 63;
  int w = __builtin_amdgcn_readfirstlane(t >> 6);
#pragma unroll 1
  for (int g = 0; g < 8; ++g) {
    float acc[8] = {0, 0, 0, 0, 0, 0, 0, 0};
    int p0 = w * 64 + g * 8;
    for (int d = 0; d < ND; ++d) {
      float fv = fl[d * 64 + lane];
#pragma unroll
      for (int u = 0; u < 8; ++u) {
        int p = p0 + u;
        int o = p & 127, sel = p >> 7;
        acc[u] += wl[o * 129 + sel * 64 + d] * fv;
      }
    }
#pragma unroll
    for (int u = 0; u < 8; ++u) {
      int p = p0 + u;
      int o = p & 127, sel = p >> 7;
      u16* outp = sel ? Bpre : Apre;
      outp[(size_t)(b * NNN + n0 + lane) * NO + o] = f2b(acc[u]);
    }
  }
}

// ---------------- intra: bf16 A/B2 gathers; max/min over k + atomic stats ----------------
__global__ __launch_bounds__(128) void k_intra(const u16* __restrict__ Apre, const u16* __restrict__ Bpre,
                                               const int* __restrict__ tidx, const float* __restrict__ td2,
                                               const float* __restrict__ wl, float* __restrict__ imax,
                                               float* __restrict__ imin, float* __restrict__ stats) {
  __shared__ int sidx[32 * NK];
  __shared__ float sdst[32 * NK];
  int t = threadIdx.x;
  int b = blockIdx.x >> 7;
  int n0 = (blockIdx.x & 127) << 5;
  for (int e = t; e < 32 * NK; e += 128) {
    int base = (b * NNN + n0 + (e >> 4)) * NK + (e & 15);
    sidx[e] = tidx[base];
    sdst[e] = sqrtf(td2[base]);
  }
  __syncthreads();
  int o = t;
  float w128 = wl[o * 129 + 128];
  float ssum = 0.f, ssq = 0.f;
  for (int c = 0; c < 32; ++c) {
    float a = b2f(Apre[(size_t)(b * NNN + n0 + c) * NO + o]);
    float mx = -3.4e38f, mn = 3.4e38f;
#pragma unroll
    for (int kx = 0; kx < NK; ++kx) {
      int id = sidx[c * NK + kx];
      float y = a + b2f(Bpre[(size_t)(b * NNN + id) * NO + o]) + w128 * sdst[c * NK + kx];
      mx = fmaxf(mx, y); mn = fminf(mn, y);
      ssum += y; ssq += y * y;
    }
    imax[(b * NO + o) * NNN + n0 + c] = mx;
    imin[(b * NO + o) * NNN + n0 + c] = mn;
  }
  atomicAdd(&stats[o], ssum);
  atomicAdd(&stats[NO + o], ssq);
}

// ---------------- sem: z = w_sem * (fgt * linv) -> [b][o][n] ----------------
__global__ __launch_bounds__(256) void k_sem(const float* __restrict__ fgt, const float* __restrict__ linv,
                                             const float* __restrict__ wsem, float* __restrict__ zsem) {
  __shared__ float fl[64 * 65];
  int t = threadIdx.x;
  int b = blockIdx.x >> 6;
  int n0 = (blockIdx.x & 63) << 6;
  for (int e = t; e < 64 * 64; e += 256) {
    int n = e >> 6, d = e & 63;
    fl[n * 65 + d] = fgt[(size_t)(b * NNN + n0 + n) * ND + d] * linv[b * NNN + n0 + n];
  }
  __syncthreads();
  int lane = t & 63;
  int ob = __builtin_amdgcn_readfirstlane((t >> 6) * 32);
#pragma unroll 1
  for (int g = 0; g < 4; ++g) {
    float acc[8] = {0, 0, 0, 0, 0, 0, 0, 0};
    for (int d = 0; d < ND; ++d) {
      float fv = fl[lane * 65 + d];
#pragma unroll
      for (int u = 0; u < 8; ++u) acc[u] += wsem[(ob + g * 8 + u) * ND + d] * fv;
    }
#pragma unroll
    for (int u = 0; u < 8; ++u)
      zsem[(b * NO + ob + g * 8 + u) * NNN + n0 + lane] = acc[u];
  }
}

// ---------------- per-channel sum/ssq over [b][o][n] (one block per o) ----------------
__global__ void k_stats(const float* __restrict__ zz, float* __restrict__ sout) {
  int o = blockIdx.x, t = threadIdx.x;
  float s = 0.f, q = 0.f;
  for (int b2 = 0; b2 < NB; ++b2) {
    const float* p = zz + (size_t)(b2 * NO + o) * NNN;
    for (int n = t; n < NNN; n += 256) { float v = p[n]; s += v; q += v * v; }
  }
#pragma unroll
  for (int off = 32; off; off >>= 1) { s += __shfl_down(s, off); q += __shfl_down(q, off); }
  __shared__ float rs[4], rq[4];
  int lane = t & 63, w = t >> 6;
  if (lane == 0) { rs[w] = s; rq[w] = q; }
  __syncthreads();
  if (t == 0) {
    sout[o]      = rs[0] + rs[1] + rs[2] + rs[3];
    sout[NO + o] = rq[0] + rq[1] + rq[2] + rq[3];
  }
}

// ---------------- finalize BN: merged intra+sem (256 threads) ----------------
__global__ void k_fin2(const float* __restrict__ stats,
                       const float* __restrict__ g1, const float* __restrict__ be1, float ci1,
                       const float* __restrict__ g2, const float* __restrict__ be2, float ci2,
                       float* __restrict__ coef) {
  int t = threadIdx.x;
  int o = t & 127;
  int which = t >> 7;
  const float* st = stats + which * 2 * NO;
  const float* g  = which ? g2 : g1;
  const float* be = which ? be2 : be1;
  float ci = which ? ci2 : ci1;
  float mean = st[o] * ci;
  float var = st[NO + o] * ci - mean * mean;
  var = var > 0.f ? var : 0.f;
  float a = g[o] * rsqrtf(var + BN_EPS);
  coef[which * 2 * NO + o] = a;
  coef[which * 2 * NO + NO + o] = be[o] - mean * a;
}

// ---------------- finalize BN single (for full) ----------------
__global__ void k_fin(const float* __restrict__ stats, const float* __restrict__ g,
                      const float* __restrict__ be, float cnt_inv, float* __restrict__ coef) {
  int o = threadIdx.x;
  float mean = stats[o] * cnt_inv;
  float var = stats[NO + o] * cnt_inv - mean * mean;
  var = var > 0.f ? var : 0.f;
  float a = g[o] * rsqrtf(var + BN_EPS);
  coef[o] = a;
  coef[NO + o] = be[o] - mean * a;
}

// ---------------- full: z = w_full * lrelu(BN(cat)) ----------------
__global__ __launch_bounds__(256) void k_full(const float* __restrict__ imax, const float* __restrict__ imin,
                                              const float* __restrict__ zsem, const float* __restrict__ wfull,
                                              const float* __restrict__ coef, float* __restrict__ zfull) {
  __shared__ float fl[2 * NO * 64];
  int t = threadIdx.x;
  int b = blockIdx.x >> 6;
  int n0 = (blockIdx.x & 63) << 6;
  for (int e = t; e < 2 * NO * 64; e += 256) {
    int c = e >> 6, col = e & 63;
    float aa, bb, x;
    if (c < NO) {
      aa = coef[c]; bb = coef[NO + c];
      const float* src = (aa >= 0.f) ? imax : imin;
      x = src[(b * NO + c) * NNN + n0 + col];
    } else {
      int c2 = c - NO;
      aa = coef[2 * NO + c2]; bb = coef[3 * NO + c2];
      x = zsem[(b * NO + c2) * NNN + n0 + col];
    }
    float y = aa * x + bb;
    fl[e] = (y >= 0.f) ? y : NEG * y;
  }
  __syncthreads();
  int lane = t & 63;
  int ob = __builtin_amdgcn_readfirstlane((t >> 6) * 32);
#pragma unroll 1
  for (int g = 0; g < 4; ++g) {
    float acc[8] = {0, 0, 0, 0, 0, 0, 0, 0};
    for (int c = 0; c < 2 * NO; ++c) {
      float fv = fl[c * 64 + lane];
#pragma unroll
      for (int u = 0; u < 8; ++u) acc[u] += wfull[(ob + g * 8 + u) * (2 * NO) + c] * fv;
    }
#pragma unroll
    for (int u = 0; u < 8; ++u)
      zfull[(b * NO + ob + g * 8 + u) * NNN + n0 + lane] = acc[u];
  }
}

// ---------------- out = lrelu(a*z + b) ----------------
__global__ void k_out(const float* __restrict__ zfull, const float* __restrict__ coef,
                      float* __restrict__ out) {
  int gid = blockIdx.x * 256 + threadIdx.x;
  int o = (gid >> 12) & 127;
  float y = coef[o] * zfull[gid] + coef[NO + o];
  out[gid] = (y >= 0.f) ? y : NEG * y;
}

extern "C" void kernel_launch(void* const* d_in, const int* in_sizes, int n_in,
                              void* d_out, int out_size, void* d_ws, size_t ws_size,
                              hipStream_t stream) {
  (void)in_sizes; (void)n_in; (void)out_size; (void)ws_size;
  const float* f       = (const float*)d_in[0];
  const float* w_local = (const float*)d_in[1];
  const float* g_local = (const float*)d_in[2];
  const float* b_local = (const float*)d_in[3];
  const float* w_sem   = (const float*)d_in[4];
  const float* g_sem   = (const float*)d_in[5];
  const float* b_sem   = (const float*)d_in[6];
  const float* w_full  = (const float*)d_in[7];
  const float* g_full  = (const float*)d_in[8];
  const float* b_full  = (const float*)d_in[9];
  const float* wq = (const float*)d_in[10];
  const float* bq = (const float*)d_in[11];
  const float* wk = (const float*)d_in[12];
  const float* bk = (const float*)d_in[13];
  const float* wv = (const float*)d_in[14];
  const float* bv = (const float*)d_in[15];
  float* Wp = (float*)d_ws;
  u16* qb16 = (u16*)(Wp + OFF_Q);
  u16* kb16 = (u16*)(Wp + OFF_K);
  u16* vb16 = (u16*)(Wp + OFF_V);
  u16* ap16 = (u16*)(Wp + OFF_APRE);
  u16* bp16 = (u16*)(Wp + OFF_BPRE);

  hipMemsetAsync(Wp + OFF_STATS, 0, 2 * NO * sizeof(float), stream);  // intra atomic stats
  k_xx  <<<NB * NNN / 256, 256, 0, stream>>>(f, Wp + OFF_XX);
  k_qkv <<<dim3(NB * NNN / 64, 3), 256, 0, stream>>>(f, wq, bq, wk, bk, wv, bv, qb16, kb16, vb16);
  k_knn <<<NB * (NNN / 8), 256, 0, stream>>>(f, Wp + OFF_XX, (int*)(Wp + OFF_IDX), Wp + OFF_D2);
  k_attn<<<NB * (NNN / 32), 256, 0, stream>>>(qb16, kb16, vb16, Wp + OFF_FGT, Wp + OFF_LINV);
  k_ab  <<<NB * (NNN / 64), 256, 0, stream>>>(f, w_local, ap16, bp16);
  k_intra<<<NB * (NNN / 32), 128, 0, stream>>>(ap16, bp16,
                                               (const int*)(Wp + OFF_IDX), Wp + OFF_D2,
                                               w_local, Wp + OFF_IMAX, Wp + OFF_IMIN, Wp + OFF_STATS);
  k_sem <<<NB * (NNN / 64), 256, 0, stream>>>(Wp + OFF_FGT, Wp + OFF_LINV, w_sem, Wp + OFF_ZSEM);
  k_stats<<<NO, 256, 0, stream>>>(Wp + OFF_ZSEM, Wp + OFF_STATS + 2 * NO);
  k_fin2<<<1, 2 * NO, 0, stream>>>(Wp + OFF_STATS,
                                   g_local, b_local, 1.f / (float)(NB * NNN * NK),
                                   g_sem, b_sem, 1.f / (float)(NB * NNN),
                                   Wp + OFF_COEF);
  k_full<<<NB * (NNN / 64), 256, 0, stream>>>(Wp + OFF_IMAX, Wp + OFF_IMIN, Wp + OFF_ZSEM,
                                              w_full, Wp + OFF_COEF, Wp + OFF_ZFULL);
  k_stats<<<NO, 256, 0, stream>>>(Wp + OFF_ZFULL, Wp + OFF_STATS + 4 * NO);
  k_fin <<<1, NO, 0, stream>>>(Wp + OFF_STATS + 4 * NO, g_full, b_full,
                               1.f / (float)(NB * NNN), Wp + OFF_COEF + 4 * NO);
  k_out <<<NB * NO * NNN / 256, 256, 0, stream>>>(Wp + OFF_ZFULL, Wp + OFF_COEF + 4 * NO,
                                                  (float*)d_out);
}

// Round 13
// 597.355 us; speedup vs baseline: 1.2950x; 1.0584x over previous
//
#include <hip/hip_runtime.h>
#include <math.h>

constexpr int NB = 4;      // batch
constexpr int ND = 64;     // feature dim
constexpr int NNN = 4096;  // points
constexpr int NO = 128;    // out channels
constexpr int NK = 16;     // k-nn
constexpr float NEG = 0.01f;
constexpr float BN_EPS = 1e-5f;

typedef unsigned short u16;
typedef unsigned int u32;
typedef __attribute__((ext_vector_type(8))) short short8;
typedef __attribute__((ext_vector_type(4))) float floatx4;

// workspace offsets (in floats)
constexpr int OFF_XX    = 0;
constexpr int OFF_IDX   = 16384;
constexpr int OFF_D2    = 278528;
constexpr int OFF_Q     = 540672;       // qb16 bf16 [b][n][d]
constexpr int OFF_K     = 1589248;      // kb16 bf16 [b][n][d]
constexpr int OFF_V     = 2637824;      // vb16 bf16 [b][d][n]
constexpr int OFF_FGT   = 3686400;      // fgt fp32 [b][n][d] (unnormalized)
constexpr int OFF_APRE  = 4734976;      // bf16 [b][n][o]
constexpr int OFF_BPRE  = 6832128;      // bf16 [b][n][o]
constexpr int OFF_IMAX  = 8929280;
constexpr int OFF_IMIN  = 11026432;
constexpr int OFF_ZSEM  = OFF_Q;
constexpr int OFF_ZFULL = OFF_V;
constexpr int OFF_STATS = 13123584;     // 6*NO: [sum_i,ssq_i | sum_s,ssq_s | sum_f,ssq_f]
constexpr int OFF_COEF  = 13124352;
constexpr int OFF_LINV  = 13125120;

__device__ __forceinline__ u16 f2b(float x) {       // fp32 -> bf16 RNE
  u32 u = __builtin_bit_cast(u32, x);
  u += 0x7fffu + ((u >> 16) & 1u);
  return (u16)(u >> 16);
}
__device__ __forceinline__ float b2f(u16 h) {
  u32 u = (u32)h << 16;
  return __builtin_bit_cast(float, u);
}

// value-only max fold step via DPP (single v_max_f32 with fused DPP src)
template <int CTRL>
__device__ __forceinline__ float fmax_dpp(float v) {
  int b = __builtin_bit_cast(int, v);
  int s = __builtin_amdgcn_update_dpp(b, b, CTRL, 0xF, 0xF, false);
  return fmaxf(v, __builtin_bit_cast(float, s));
}
// (value,col) pair fold: larger value wins; tie -> keep left (smaller col by construction)
__device__ __forceinline__ void pairmax(float av, int ai, float bv, int bi, float& rv, int& ri) {
  bool tk = bv > av;
  rv = tk ? bv : av;
  ri = tk ? bi : ai;
}

// ---------------- q/k/v = W f + bias -> bf16; sel==0 also emits xx (fused k_xx) ----------------
__global__ __launch_bounds__(256) void k_qkv(const float* __restrict__ f,
    const float* __restrict__ wq, const float* __restrict__ bq,
    const float* __restrict__ wk, const float* __restrict__ bk,
    const float* __restrict__ wv, const float* __restrict__ bv,
    u16* __restrict__ qb, u16* __restrict__ kb, u16* __restrict__ vb,
    float* __restrict__ xx) {
  int sel = blockIdx.y;
  const float* W    = (sel == 0) ? wq : (sel == 1) ? wk : wv;
  const float* bias = (sel == 0) ? bq : (sel == 1) ? bk : bv;
  int t = threadIdx.x;
  int lane = t & 63;
  int og = __builtin_amdgcn_readfirstlane(t >> 6);
  int gcol = blockIdx.x * 64 + lane;
  int b = gcol >> 12, n = gcol & 4095;
  const float* fb = f + b * ND * NNN + n;
  float cv[64];
#pragma unroll
  for (int d = 0; d < ND; ++d) cv[d] = fb[d * NNN];
  if (sel == 0 && og == 0) {              // fused k_xx: identical d-order sum
    float s = 0.f;
#pragma unroll
    for (int d = 0; d < ND; ++d) s += cv[d] * cv[d];
    xx[b * NNN + n] = s;
  }
  float acc[16];
#pragma unroll 1
  for (int oi = 0; oi < 16; ++oi) {
    int o = og * 16 + oi;
    const float* wr = W + o * ND;
    float a = bias[o];
#pragma unroll
    for (int d = 0; d < ND; ++d) a += wr[d] * cv[d];
    acc[oi] = a;
  }
  if (sel == 2) {
#pragma unroll
    for (int oi = 0; oi < 16; ++oi)
      vb[(size_t)(b * ND + og * 16 + oi) * NNN + n] = f2b(acc[oi]);
  } else {
    short8 p0, p1;
#pragma unroll
    for (int oi = 0; oi < 8; ++oi) { p0[oi] = (short)f2b(acc[oi]); p1[oi] = (short)f2b(acc[8 + oi]); }
    u16* dst = (sel ? kb : qb) + (size_t)(b * NNN + n) * ND + og * 16;
    *(short8*)dst = p0;
    *(short8*)(dst + 8) = p1;
  }
}

// ---------------- kNN v6 (proven): 8 rows/block, col-halves of 2048,
// float4 loads, lane-leaf tournament with DPP value fold ----------------
__global__ __launch_bounds__(256, 4) void k_knn(const float* __restrict__ f, const float* __restrict__ xx,
                                                int* __restrict__ tidx, float* __restrict__ td2) {
  __shared__ __align__(16) float fm[ND * 8];   // [d][r] row fragments (2 KB)
  __shared__ __align__(16) float sl[4 * 2048]; // 4 rows x 2048 cols (32 KB)
  int t = threadIdx.x;
  int lane = t & 63;
  int w = __builtin_amdgcn_readfirstlane(t >> 6);
  int b = blockIdx.x >> 9;
  int m0 = (blockIdx.x & 511) << 3;
  const float* fb = f + b * ND * NNN;
  { int e = t;       int d = e >> 3, r = e & 7; fm[e] = fb[d * NNN + m0 + r]; }
  { int e = t + 256; int d = e >> 3, r = e & 7; fm[e] = fb[d * NNN + m0 + r]; }
  __syncthreads();
  float lv[2][2];
  int   li[2][2];
#pragma unroll
  for (int h = 0; h < 2; ++h) {
    float acc[64];
#pragma unroll
    for (int i = 0; i < 64; ++i) acc[i] = 0.f;
    for (int d = 0; d < ND; ++d) {
      const float* frow = fb + d * NNN + h * 2048 + 4 * t;
      float4 v0 = *(const float4*)(frow);
      float4 v1 = *(const float4*)(frow + 1024);
      float4 r0 = *(const float4*)&fm[d * 8];
      float4 r1 = *(const float4*)&fm[d * 8 + 4];
      float va0[4] = {v0.x, v0.y, v0.z, v0.w};
      float va1[4] = {v1.x, v1.y, v1.z, v1.w};
      float rr[8]  = {r0.x, r0.y, r0.z, r0.w, r1.x, r1.y, r1.z, r1.w};
#pragma unroll
      for (int c2 = 0; c2 < 4; ++c2)
#pragma unroll
        for (int r = 0; r < 8; ++r) {
          acc[c2 * 8 + r]      += va0[c2] * rr[r];
          acc[32 + c2 * 8 + r] += va1[c2] * rr[r];
        }
    }
    {
      const float* xrow = xx + b * NNN + h * 2048 + 4 * t;
      float4 x0 = *(const float4*)(xrow);
      float4 x1 = *(const float4*)(xrow + 1024);
      float xa0[4] = {x0.x, x0.y, x0.z, x0.w};
      float xa1[4] = {x1.x, x1.y, x1.z, x1.w};
#pragma unroll
      for (int c2 = 0; c2 < 4; ++c2)
#pragma unroll
        for (int r = 0; r < 8; ++r) {
          acc[c2 * 8 + r]      = 2.f * acc[c2 * 8 + r]      - xa0[c2];
          acc[32 + c2 * 8 + r] = 2.f * acc[32 + c2 * 8 + r] - xa1[c2];
        }
    }
#pragma unroll
    for (int s = 0; s < 2; ++s) {
      __syncthreads();
#pragma unroll
      for (int r4 = 0; r4 < 4; ++r4) {
        int r = s * 4 + r4;
#pragma unroll
        for (int jj = 0; jj < 2; ++jj) {
          float4 w4;
          w4.x = acc[jj * 32 + 0 * 8 + r];
          w4.y = acc[jj * 32 + 1 * 8 + r];
          w4.z = acc[jj * 32 + 2 * 8 + r];
          w4.w = acc[jj * 32 + 3 * 8 + r];
          *(float4*)&sl[r4 * 2048 + jj * 1024 + 4 * t] = w4;
        }
      }
      __syncthreads();
      float vals[32];
#pragma unroll
      for (int i = 0; i < 32; ++i) vals[i] = sl[w * 2048 + i * 64 + lane];
      float gv[8]; int gi[8];
#pragma unroll
      for (int g = 0; g < 8; ++g) {
        float v0 = vals[g * 4]; int i0 = (g * 4) * 64 + lane;
#pragma unroll
        for (int k2 = 1; k2 < 4; ++k2)
          pairmax(v0, i0, vals[g * 4 + k2], (g * 4 + k2) * 64 + lane, v0, i0);
        gv[g] = v0; gi[g] = i0;
      }
      float t1v[4]; int t1i[4];
      float t2v[2]; int t2i[2];
      float lvv; int lii;
#pragma unroll
      for (int p = 0; p < 4; ++p) pairmax(gv[2 * p], gi[2 * p], gv[2 * p + 1], gi[2 * p + 1], t1v[p], t1i[p]);
#pragma unroll
      for (int q = 0; q < 2; ++q) pairmax(t1v[2 * q], t1i[2 * q], t1v[2 * q + 1], t1i[2 * q + 1], t2v[q], t2i[q]);
      pairmax(t2v[0], t2i[0], t2v[1], t2i[1], lvv, lii);
      float selv = 0.f; int seli = 0;
#pragma unroll 1
      for (int kx = 0; kx < NK; ++kx) {
        float W = lvv;
        W = fmax_dpp<0xB1>(W);            // quad_perm xor1
        W = fmax_dpp<0x4E>(W);            // quad_perm xor2
        W = fmax_dpp<0x124>(W);           // row_ror:4
        W = fmax_dpp<0x128>(W);           // row_ror:8
        W = fmaxf(W, __shfl_xor(W, 16));
        W = fmaxf(W, __shfl_xor(W, 32));
        unsigned long long mk = __ballot(lvv == W);
        int lw = (int)__ffsll(mk) - 1;
        int wcol = __builtin_amdgcn_readlane(lii, lw);
        if (lane == kx) { selv = W; seli = wcol; }
        int jw = wcol >> 6;
#pragma unroll
        for (int g = 0; g < 8; ++g)
          if (g == (jw >> 2)) {
#pragma unroll
            for (int k2 = 0; k2 < 4; ++k2)
              if (k2 == (jw & 3))
                vals[g * 4 + k2] = (lane == lw) ? -3.0e38f : vals[g * 4 + k2];
            float v0 = vals[g * 4]; int i0 = (g * 4) * 64 + lane;
#pragma unroll
            for (int k2 = 1; k2 < 4; ++k2)
              pairmax(v0, i0, vals[g * 4 + k2], (g * 4 + k2) * 64 + lane, v0, i0);
            gv[g] = v0; gi[g] = i0;
            int p = g >> 1;
            pairmax(gv[2 * p], gi[2 * p], gv[2 * p + 1], gi[2 * p + 1], t1v[p], t1i[p]);
            int q = p >> 1;
            pairmax(t1v[2 * q], t1i[2 * q], t1v[2 * q + 1], t1i[2 * q + 1], t2v[q], t2i[q]);
            pairmax(t2v[0], t2i[0], t2v[1], t2i[1], lvv, lii);
          }
      }
      lv[h][s] = selv; li[h][s] = h * 2048 + seli;
    }
  }
#pragma unroll
  for (int s = 0; s < 2; ++s) {
    int m = m0 + s * 4 + w;
    float xm = xx[b * NNN + m];
    float a   = lv[0][s]; int ai  = li[0][s];
    float bb2 = lv[1][s]; int bi2 = li[1][s];
    int cntB = 0, cntA = 0;
#pragma unroll
    for (int j = 0; j < 16; ++j) {
      float bj = __shfl(bb2, j);
      cntB += (bj > a) ? 1 : 0;
      float aj = __shfl(a, j);
      cntA += (aj >= bb2) ? 1 : 0;
    }
    if (lane < 16) {
      int base = (b * NNN + m) * NK;
      int rA = lane + cntB;
      int rB = lane + cntA;
      if (rA < NK) {
        float dd = xm - a;
        tidx[base + rA] = ai;
        td2[base + rA] = dd > 0.f ? dd : 0.f;
      }
      if (rB < NK) {
        float dd = xm - bb2;
        tidx[base + rB] = bi2;
        td2[base + rB] = dd > 0.f ? dd : 0.f;
      }
    }
  }
}

// ---------------- attention v2: 32 q-rows/block (K/V loaded once per 2 row-tiles) ----------------
__global__ __launch_bounds__(256) void k_attn(const u16* __restrict__ qb,
                                              const u16* __restrict__ kb,
                                              const u16* __restrict__ vb,
                                              float* __restrict__ fgt,
                                              float* __restrict__ linv) {
  __shared__ __align__(16) u16 P[32 * 520];   // 33.3 KB
  __shared__ float rsum[4][32];
  int t = threadIdx.x;
  int lane = t & 63;
  int w = __builtin_amdgcn_readfirstlane(t >> 6);
  int quad = lane >> 4;
  int l15 = lane & 15;
  int b = blockIdx.x >> 7;
  int m0 = (blockIdx.x & 127) << 5;
  const u16* qra = qb + (size_t)(b * NNN + m0 + l15) * ND + quad * 8;
  const u16* qrb = qb + (size_t)(b * NNN + m0 + 16 + l15) * ND + quad * 8;
  short8 qa0a = *(const short8*)(qra), qa1a = *(const short8*)(qra + 32);
  short8 qa0b = *(const short8*)(qrb), qa1b = *(const short8*)(qrb + 32);
  const u16* kbase = kb + (size_t)b * NNN * ND;
  const u16* vrow  = vb + (size_t)(b * ND + w * 16 + l15) * NNN;
  floatx4 c2a = {0.f, 0.f, 0.f, 0.f};
  floatx4 c2b = {0.f, 0.f, 0.f, 0.f};
  float rsa[4] = {0.f, 0.f, 0.f, 0.f};
  float rsb[4] = {0.f, 0.f, 0.f, 0.f};
#pragma unroll 1
  for (int it = 0; it < 8; ++it) {
    int nchunk = it * 512;
#pragma unroll 1
    for (int ct = 0; ct < 8; ++ct) {
      int cc0 = (w * 8 + ct) * 16;
      const u16* krow = kbase + (size_t)(nchunk + cc0 + l15) * ND + quad * 8;
      short8 kf0 = *(const short8*)(krow);
      short8 kf1 = *(const short8*)(krow + 32);
      floatx4 acca = {0.f, 0.f, 0.f, 0.f};
      acca = __builtin_amdgcn_mfma_f32_16x16x32_bf16(qa0a, kf0, acca, 0, 0, 0);
      acca = __builtin_amdgcn_mfma_f32_16x16x32_bf16(qa1a, kf1, acca, 0, 0, 0);
      floatx4 accb = {0.f, 0.f, 0.f, 0.f};
      accb = __builtin_amdgcn_mfma_f32_16x16x32_bf16(qa0b, kf0, accb, 0, 0, 0);
      accb = __builtin_amdgcn_mfma_f32_16x16x32_bf16(qa1b, kf1, accb, 0, 0, 0);
      int ccol = cc0 + l15;
#pragma unroll
      for (int r = 0; r < 4; ++r) {
        float ea = __expf(acca[r] * 0.125f);
        rsa[r] += ea;
        P[(quad * 4 + r) * 520 + ccol] = f2b(ea);
        float eb = __expf(accb[r] * 0.125f);
        rsb[r] += eb;
        P[(16 + quad * 4 + r) * 520 + ccol] = f2b(eb);
      }
    }
    __syncthreads();
    const u16* vp = vrow + nchunk + quad * 8;
#pragma unroll
    for (int kk = 0; kk < 16; ++kk) {
      short8 b2 = *(const short8*)(vp + kk * 32);
      short8 a2a = *(const short8*)&P[l15 * 520 + kk * 32 + quad * 8];
      short8 a2b = *(const short8*)&P[(16 + l15) * 520 + kk * 32 + quad * 8];
      c2a = __builtin_amdgcn_mfma_f32_16x16x32_bf16(a2a, b2, c2a, 0, 0, 0);
      c2b = __builtin_amdgcn_mfma_f32_16x16x32_bf16(a2b, b2, c2b, 0, 0, 0);
    }
    __syncthreads();
  }
#pragma unroll
  for (int r = 0; r < 4; ++r) {
    float va = rsa[r];
    va += __shfl_xor(va, 1); va += __shfl_xor(va, 2);
    va += __shfl_xor(va, 4); va += __shfl_xor(va, 8);
    rsa[r] = va;
    float vb2 = rsb[r];
    vb2 += __shfl_xor(vb2, 1); vb2 += __shfl_xor(vb2, 2);
    vb2 += __shfl_xor(vb2, 4); vb2 += __shfl_xor(vb2, 8);
    rsb[r] = vb2;
  }
  if (l15 == 0) {
#pragma unroll
    for (int r = 0; r < 4; ++r) {
      rsum[w][quad * 4 + r] = rsa[r];
      rsum[w][16 + quad * 4 + r] = rsb[r];
    }
  }
#pragma unroll
  for (int r = 0; r < 4; ++r) {
    fgt[(size_t)(b * NNN + m0 + quad * 4 + r) * ND + w * 16 + l15] = c2a[r];
    fgt[(size_t)(b * NNN + m0 + 16 + quad * 4 + r) * ND + w * 16 + l15] = c2b[r];
  }
  __syncthreads();
  if (t < 32) {
    float s = rsum[0][t] + rsum[1][t] + rsum[2][t] + rsum[3][t];
    linv[b * NNN + m0 + t] = 1.f / s;
  }
}

// ---------------- A/B2 pre-GEMMs: fp32 compute, bf16 store [b][n][o] ----------------
__global__ __launch_bounds__(256) void k_ab(const float* __restrict__ f, const float* __restrict__ wl,
                                            u16* __restrict__ Apre, u16* __restrict__ Bpre) {
  __shared__ float fl[ND * 64];
  int t = threadIdx.x;
  int b = blockIdx.x >> 6;
  int n0 = (blockIdx.x & 63) << 6;
  for (int e = t; e < ND * 64; e += 256) {
    int d = e >> 6, c = e & 63;
    fl[e] = f[b * ND * NNN + d * NNN + n0 + c];
  }
  __syncthreads();
  int lane = t & 63;
  int w = __builtin_amdgcn_readfirstlane(t >> 6);
#pragma unroll 1
  for (int g = 0; g < 8; ++g) {
    float acc[8] = {0, 0, 0, 0, 0, 0, 0, 0};
    int p0 = w * 64 + g * 8;
    for (int d = 0; d < ND; ++d) {
      float fv = fl[d * 64 + lane];
#pragma unroll
      for (int u = 0; u < 8; ++u) {
        int p = p0 + u;
        int o = p & 127, sel = p >> 7;
        acc[u] += wl[o * 129 + sel * 64 + d] * fv;
      }
    }
#pragma unroll
    for (int u = 0; u < 8; ++u) {
      int p = p0 + u;
      int o = p & 127, sel = p >> 7;
      u16* outp = sel ? Bpre : Apre;
      outp[(size_t)(b * NNN + n0 + lane) * NO + o] = f2b(acc[u]);
    }
  }
}

// ---------------- intra: 256 thr (2 col-halves), bf16 gathers, max/min + atomic stats ----------------
__global__ __launch_bounds__(256) void k_intra(const u16* __restrict__ Apre, const u16* __restrict__ Bpre,
                                               const int* __restrict__ tidx, const float* __restrict__ td2,
                                               const float* __restrict__ wl, float* __restrict__ imax,
                                               float* __restrict__ imin, float* __restrict__ stats) {
  __shared__ int sidx[32 * NK];
  __shared__ float sdst[32 * NK];
  __shared__ float ps[128], pq[128];
  int t = threadIdx.x;
  int b = blockIdx.x >> 7;
  int n0 = (blockIdx.x & 127) << 5;
  for (int e = t; e < 32 * NK; e += 256) {
    int base = (b * NNN + n0 + (e >> 4)) * NK + (e & 15);
    sidx[e] = tidx[base];
    sdst[e] = sqrtf(td2[base]);
  }
  __syncthreads();
  int o = t & 127;
  int ch = t >> 7;                         // col half: 0 -> cols 0..15, 1 -> 16..31
  float w128 = wl[o * 129 + 128];
  float ssum = 0.f, ssq = 0.f;
  for (int c = ch * 16; c < ch * 16 + 16; ++c) {
    float a = b2f(Apre[(size_t)(b * NNN + n0 + c) * NO + o]);
    float mx = -3.4e38f, mn = 3.4e38f;
#pragma unroll
    for (int kx = 0; kx < NK; ++kx) {
      int id = sidx[c * NK + kx];
      float y = a + b2f(Bpre[(size_t)(b * NNN + id) * NO + o]) + w128 * sdst[c * NK + kx];
      mx = fmaxf(mx, y); mn = fminf(mn, y);
      ssum += y; ssq += y * y;
    }
    imax[(b * NO + o) * NNN + n0 + c] = mx;
    imin[(b * NO + o) * NNN + n0 + c] = mn;
  }
  if (t >= 128) { ps[o] = ssum; pq[o] = ssq; }
  __syncthreads();
  if (t < 128) {
    atomicAdd(&stats[o], ssum + ps[o]);
    atomicAdd(&stats[NO + o], ssq + pq[o]);
  }
}

// ---------------- sem: z = w_sem * (fgt * linv) -> [b][o][n] ----------------
__global__ __launch_bounds__(256) void k_sem(const float* __restrict__ fgt, const float* __restrict__ linv,
                                             const float* __restrict__ wsem, float* __restrict__ zsem) {
  __shared__ float fl[64 * 65];
  int t = threadIdx.x;
  int b = blockIdx.x >> 6;
  int n0 = (blockIdx.x & 63) << 6;
  for (int e = t; e < 64 * 64; e += 256) {
    int n = e >> 6, d = e & 63;
    fl[n * 65 + d] = fgt[(size_t)(b * NNN + n0 + n) * ND + d] * linv[b * NNN + n0 + n];
  }
  __syncthreads();
  int lane = t & 63;
  int ob = __builtin_amdgcn_readfirstlane((t >> 6) * 32);
#pragma unroll 1
  for (int g = 0; g < 4; ++g) {
    float acc[8] = {0, 0, 0, 0, 0, 0, 0, 0};
    for (int d = 0; d < ND; ++d) {
      float fv = fl[lane * 65 + d];
#pragma unroll
      for (int u = 0; u < 8; ++u) acc[u] += wsem[(ob + g * 8 + u) * ND + d] * fv;
    }
#pragma unroll
    for (int u = 0; u < 8; ++u)
      zsem[(b * NO + ob + g * 8 + u) * NNN + n0 + lane] = acc[u];
  }
}

// ---------------- per-channel sum/ssq: grid (NO, NB), atomic accumulate ----------------
__global__ void k_stats(const float* __restrict__ zz, float* __restrict__ sout) {
  int o = blockIdx.x, b2 = blockIdx.y, t = threadIdx.x;
  const float* p = zz + (size_t)(b2 * NO + o) * NNN;
  float s = 0.f, q = 0.f;
  for (int n = t; n < NNN; n += 256) { float v = p[n]; s += v; q += v * v; }
#pragma unroll
  for (int off = 32; off; off >>= 1) { s += __shfl_down(s, off); q += __shfl_down(q, off); }
  __shared__ float rs[4], rq[4];
  int lane = t & 63, w = t >> 6;
  if (lane == 0) { rs[w] = s; rq[w] = q; }
  __syncthreads();
  if (t == 0) {
    atomicAdd(&sout[o],      rs[0] + rs[1] + rs[2] + rs[3]);
    atomicAdd(&sout[NO + o], rq[0] + rq[1] + rq[2] + rq[3]);
  }
}

// ---------------- finalize BN: merged intra+sem (256 threads) ----------------
__global__ void k_fin2(const float* __restrict__ stats,
                       const float* __restrict__ g1, const float* __restrict__ be1, float ci1,
                       const float* __restrict__ g2, const float* __restrict__ be2, float ci2,
                       float* __restrict__ coef) {
  int t = threadIdx.x;
  int o = t & 127;
  int which = t >> 7;
  const float* st = stats + which * 2 * NO;
  const float* g  = which ? g2 : g1;
  const float* be = which ? be2 : be1;
  float ci = which ? ci2 : ci1;
  float mean = st[o] * ci;
  float var = st[NO + o] * ci - mean * mean;
  var = var > 0.f ? var : 0.f;
  float a = g[o] * rsqrtf(var + BN_EPS);
  coef[which * 2 * NO + o] = a;
  coef[which * 2 * NO + NO + o] = be[o] - mean * a;
}

// ---------------- full: z = w_full * lrelu(BN(cat)) ----------------
__global__ __launch_bounds__(256) void k_full(const float* __restrict__ imax, const float* __restrict__ imin,
                                              const float* __restrict__ zsem, const float* __restrict__ wfull,
                                              const float* __restrict__ coef, float* __restrict__ zfull) {
  __shared__ float fl[2 * NO * 64];
  int t = threadIdx.x;
  int b = blockIdx.x >> 6;
  int n0 = (blockIdx.x & 63) << 6;
  for (int e = t; e < 2 * NO * 64; e += 256) {
    int c = e >> 6, col = e & 63;
    float aa, bb, x;
    if (c < NO) {
      aa = coef[c]; bb = coef[NO + c];
      const float* src = (aa >= 0.f) ? imax : imin;
      x = src[(b * NO + c) * NNN + n0 + col];
    } else {
      int c2 = c - NO;
      aa = coef[2 * NO + c2]; bb = coef[3 * NO + c2];
      x = zsem[(b * NO + c2) * NNN + n0 + col];
    }
    float y = aa * x + bb;
    fl[e] = (y >= 0.f) ? y : NEG * y;
  }
  __syncthreads();
  int lane = t & 63;
  int ob = __builtin_amdgcn_readfirstlane((t >> 6) * 32);
#pragma unroll 1
  for (int g = 0; g < 4; ++g) {
    float acc[8] = {0, 0, 0, 0, 0, 0, 0, 0};
    for (int c = 0; c < 2 * NO; ++c) {
      float fv = fl[c * 64 + lane];
#pragma unroll
      for (int u = 0; u < 8; ++u) acc[u] += wfull[(ob + g * 8 + u) * (2 * NO) + c] * fv;
    }
#pragma unroll
    for (int u = 0; u < 8; ++u)
      zfull[(b * NO + ob + g * 8 + u) * NNN + n0 + lane] = acc[u];
  }
}

// ---------------- out = lrelu(a*z + b), BN finalize inlined (same fp sequence as k_fin) ----------------
__global__ void k_out(const float* __restrict__ zfull, const float* __restrict__ stats,
                      const float* __restrict__ g, const float* __restrict__ be, float ci,
                      float* __restrict__ out) {
  int gid = blockIdx.x * 256 + threadIdx.x;
  int o = (gid >> 12) & 127;
  float mean = stats[o] * ci;
  float var = stats[NO + o] * ci - mean * mean;
  var = var > 0.f ? var : 0.f;
  float a = g[o] * rsqrtf(var + BN_EPS);
  float bb = be[o] - mean * a;
  float y = a * zfull[gid] + bb;
  out[gid] = (y >= 0.f) ? y : NEG * y;
}

extern "C" void kernel_launch(void* const* d_in, const int* in_sizes, int n_in,
                              void* d_out, int out_size, void* d_ws, size_t ws_size,
                              hipStream_t stream) {
  (void)in_sizes; (void)n_in; (void)out_size; (void)ws_size;
  const float* f       = (const float*)d_in[0];
  const float* w_local = (const float*)d_in[1];
  const float* g_local = (const float*)d_in[2];
  const float* b_local = (const float*)d_in[3];
  const float* w_sem   = (const float*)d_in[4];
  const float* g_sem   = (const float*)d_in[5];
  const float* b_sem   = (const float*)d_in[6];
  const float* w_full  = (const float*)d_in[7];
  const float* g_full  = (const float*)d_in[8];
  const float* b_full  = (const float*)d_in[9];
  const float* wq = (const float*)d_in[10];
  const float* bq = (const float*)d_in[11];
  const float* wk = (const float*)d_in[12];
  const float* bk = (const float*)d_in[13];
  const float* wv = (const float*)d_in[14];
  const float* bv = (const float*)d_in[15];
  float* Wp = (float*)d_ws;
  u16* qb16 = (u16*)(Wp + OFF_Q);
  u16* kb16 = (u16*)(Wp + OFF_K);
  u16* vb16 = (u16*)(Wp + OFF_V);
  u16* ap16 = (u16*)(Wp + OFF_APRE);
  u16* bp16 = (u16*)(Wp + OFF_BPRE);

  hipMemsetAsync(Wp + OFF_STATS, 0, 6 * NO * sizeof(float), stream);  // intra+sem+full stats
  k_qkv <<<dim3(NB * NNN / 64, 3), 256, 0, stream>>>(f, wq, bq, wk, bk, wv, bv,
                                                     qb16, kb16, vb16, Wp + OFF_XX);
  k_knn <<<NB * (NNN / 8), 256, 0, stream>>>(f, Wp + OFF_XX, (int*)(Wp + OFF_IDX), Wp + OFF_D2);
  k_attn<<<NB * (NNN / 32), 256, 0, stream>>>(qb16, kb16, vb16, Wp + OFF_FGT, Wp + OFF_LINV);
  k_ab  <<<NB * (NNN / 64), 256, 0, stream>>>(f, w_local, ap16, bp16);
  k_intra<<<NB * (NNN / 32), 256, 0, stream>>>(ap16, bp16,
                                               (const int*)(Wp + OFF_IDX), Wp + OFF_D2,
                                               w_local, Wp + OFF_IMAX, Wp + OFF_IMIN, Wp + OFF_STATS);
  k_sem <<<NB * (NNN / 64), 256, 0, stream>>>(Wp + OFF_FGT, Wp + OFF_LINV, w_sem, Wp + OFF_ZSEM);
  k_stats<<<dim3(NO, NB), 256, 0, stream>>>(Wp + OFF_ZSEM, Wp + OFF_STATS + 2 * NO);
  k_fin2<<<1, 2 * NO, 0, stream>>>(Wp + OFF_STATS,
                                   g_local, b_local, 1.f / (float)(NB * NNN * NK),
                                   g_sem, b_sem, 1.f / (float)(NB * NNN),
                                   Wp + OFF_COEF);
  k_full<<<NB * (NNN / 64), 256, 0, stream>>>(Wp + OFF_IMAX, Wp + OFF_IMIN, Wp + OFF_ZSEM,
                                              w_full, Wp + OFF_COEF, Wp + OFF_ZFULL);
  k_stats<<<dim3(NO, NB), 256, 0, stream>>>(Wp + OFF_ZFULL, Wp + OFF_STATS + 4 * NO);
  k_out <<<NB * NO * NNN / 256, 256, 0, stream>>>(Wp + OFF_ZFULL, Wp + OFF_STATS + 4 * NO,
                                                  g_full, b_full, 1.f / (float)(NB * NNN),
                                                  (float*)d_out);
}